// Round 2
// baseline (264.474 us; speedup 1.0000x reference)
//
#include <hip/hip_runtime.h>
#include <math.h>

#define NND 20000
#define NE  320000
#define NF  128
#define NRBF 20
#define NPB 8   // nodes per reduce block

typedef float f32x2 __attribute__((ext_vector_type(2)));

static constexpr float FCUT = 5.0f;
static constexpr float FEPS = 1e-8f;
static constexpr float PIC  = 3.14159265358979323846f / 5.0f;  // pi / CUTOFF

// ---------------- histogram of destination nodes ----------------
__global__ __launch_bounds__(256) void hist_k(const float* __restrict__ r,
                                              int* __restrict__ counts) {
    int e = blockIdx.x * 256 + threadIdx.x;
    if (e < NE) {
        int j = (int)r[(size_t)e * 5 + 1];
        atomicAdd(&counts[j], 1);
    }
}

// ---------------- exclusive scan (20000 elems, 1 block) ----------------
__global__ __launch_bounds__(1024) void scan_k(int* counts_cursor,
                                               int* offsets) {
    __shared__ int part[1024];
    const int CH = 20;  // 1024*20 = 20480 >= 20000
    int t = threadIdx.x;
    int base = t * CH;
    int loc[CH];
    int sum = 0;
#pragma unroll
    for (int i = 0; i < CH; i++) {
        int idx = base + i;
        int c = (idx < NND) ? counts_cursor[idx] : 0;
        loc[i] = sum;
        sum += c;
    }
    part[t] = sum;
    __syncthreads();
    for (int off = 1; off < 1024; off <<= 1) {
        int val = (t >= off) ? part[t - off] : 0;
        __syncthreads();
        part[t] += val;
        __syncthreads();
    }
    int excl = part[t] - sum;
#pragma unroll
    for (int i = 0; i < CH; i++) {
        int idx = base + i;
        if (idx < NND) {
            int o = excl + loc[i];
            offsets[idx] = o;
            counts_cursor[idx] = o;
        }
    }
    if (t == 1023) offsets[NND] = part[1023];
}

// ---------------- scatter edges into CSR order, precompute dir/norm ----------------
__global__ __launch_bounds__(256) void scatter_k(const float* __restrict__ r,
                                                 int* __restrict__ cursor,
                                                 float4* __restrict__ payload) {
    int e = blockIdx.x * 256 + threadIdx.x;
    if (e >= NE) return;
    const float* re = r + (size_t)e * 5;
    int j = (int)re[1];
    float x = re[2], y = re[3], z = re[4];
    float nrm = sqrtf(x * x + y * y + z * z);
    float inv = 1.0f / ((nrm + FEPS) * (nrm + FEPS));
    int pos = atomicAdd(&cursor[j], 1);
    payload[pos] = make_float4(x * inv, y * inv, z * inv, nrm);
}

// ---------------- h = silu(s @ W1 + b1) ----------------
// 64-node tile per block, 256 threads, 4x8 register tile each (pk_fma packed).
__global__ __launch_bounds__(256) void gemm_h_k(const float* __restrict__ s,
                                                const float* __restrict__ W1,
                                                const float* __restrict__ b1,
                                                float* __restrict__ h) {
    __shared__ float sT[128][68];  // transposed tile, padded
    int node0 = blockIdx.x * 64;
    int tid = threadIdx.x;
    for (int i = tid; i < 64 * 128; i += 256) {
        int n = i >> 7, k = i & 127;
        int node = node0 + n;
        sT[k][n] = (node < NND) ? s[(size_t)node * NF + k] : 0.0f;
    }
    __syncthreads();
    int tf = tid & 15, tn = tid >> 4;
    f32x2 acc[4][4];  // 4 nodes x 8 features (as 4 f32x2 pairs)
#pragma unroll
    for (int i = 0; i < 4; i++)
#pragma unroll
        for (int j2 = 0; j2 < 4; j2++) acc[i][j2] = (f32x2)(0.0f);
    const f32x2* Wp = (const f32x2*)(W1 + tf * 8);
    for (int k = 0; k < 128; k++) {
        f32x2 bp0 = Wp[(size_t)k * 64 + 0];
        f32x2 bp1 = Wp[(size_t)k * 64 + 1];
        f32x2 bp2 = Wp[(size_t)k * 64 + 2];
        f32x2 bp3 = Wp[(size_t)k * 64 + 3];
        float4 a = *(const float4*)(&sT[k][tn * 4]);
        float av[4] = {a.x, a.y, a.z, a.w};
#pragma unroll
        for (int i = 0; i < 4; i++) {
            f32x2 as = {av[i], av[i]};
            acc[i][0] = __builtin_elementwise_fma(as, bp0, acc[i][0]);
            acc[i][1] = __builtin_elementwise_fma(as, bp1, acc[i][1]);
            acc[i][2] = __builtin_elementwise_fma(as, bp2, acc[i][2]);
            acc[i][3] = __builtin_elementwise_fma(as, bp3, acc[i][3]);
        }
    }
#pragma unroll
    for (int i = 0; i < 4; i++) {
        int node = node0 + tn * 4 + i;
        if (node >= NND) continue;
#pragma unroll
        for (int j2 = 0; j2 < 4; j2++) {
            int f = tf * 8 + j2 * 2;
            f32x2 x = acc[i][j2] + *(const f32x2*)(b1 + f);
            f32x2 out;
            out.x = x.x / (1.0f + __expf(-x.x));
            out.y = x.y / (1.0f + __expf(-x.y));
            *(f32x2*)(h + (size_t)node * NF + f) = out;
        }
    }
}

// ---------------- phi = h @ W2 + b2  (384 cols in 3 chunks of 128) ----------------
__global__ __launch_bounds__(256) void gemm_phi_k(const float* __restrict__ h,
                                                  const float* __restrict__ W2,
                                                  const float* __restrict__ b2,
                                                  float* __restrict__ phi) {
    __shared__ float hT[128][68];
    int node0 = blockIdx.x * 64;
    int c = blockIdx.y;  // 0..2
    int tid = threadIdx.x;
    for (int i = tid; i < 64 * 128; i += 256) {
        int n = i >> 7, k = i & 127;
        int node = node0 + n;
        hT[k][n] = (node < NND) ? h[(size_t)node * NF + k] : 0.0f;
    }
    __syncthreads();
    int tf = tid & 15, tn = tid >> 4;
    f32x2 acc[4][4];
#pragma unroll
    for (int i = 0; i < 4; i++)
#pragma unroll
        for (int j2 = 0; j2 < 4; j2++) acc[i][j2] = (f32x2)(0.0f);
    const f32x2* Wp = (const f32x2*)(W2 + c * NF + tf * 8);
    for (int k = 0; k < 128; k++) {
        f32x2 bp0 = Wp[(size_t)k * 192 + 0];
        f32x2 bp1 = Wp[(size_t)k * 192 + 1];
        f32x2 bp2 = Wp[(size_t)k * 192 + 2];
        f32x2 bp3 = Wp[(size_t)k * 192 + 3];
        float4 a = *(const float4*)(&hT[k][tn * 4]);
        float av[4] = {a.x, a.y, a.z, a.w};
#pragma unroll
        for (int i = 0; i < 4; i++) {
            f32x2 as = {av[i], av[i]};
            acc[i][0] = __builtin_elementwise_fma(as, bp0, acc[i][0]);
            acc[i][1] = __builtin_elementwise_fma(as, bp1, acc[i][1]);
            acc[i][2] = __builtin_elementwise_fma(as, bp2, acc[i][2]);
            acc[i][3] = __builtin_elementwise_fma(as, bp3, acc[i][3]);
        }
    }
#pragma unroll
    for (int i = 0; i < 4; i++) {
        int node = node0 + tn * 4 + i;
        if (node >= NND) continue;
#pragma unroll
        for (int j2 = 0; j2 < 4; j2++) {
            int f = c * NF + tf * 8 + j2 * 2;
            f32x2 x = acc[i][j2] + *(const f32x2*)(b2 + f);
            *(f32x2*)(phi + (size_t)node * 384 + f) = x;
        }
    }
}

// ---------------- per-node reduction over its edges + output write ----------------
// 8 nodes per block; Wr columns persist in registers across all 8 nodes.
__global__ __launch_bounds__(128) void reduce_k(const int* __restrict__ offsets,
                                                const float4* __restrict__ payload,
                                                const float* __restrict__ phi,
                                                const float* __restrict__ v,
                                                const float* __restrict__ Wr,
                                                const float* __restrict__ br,
                                                float* __restrict__ dv,
                                                float* __restrict__ ds) {
    int f = threadIdx.x;
    // hoist Wr columns f, f+128, f+256 into registers as f32x2 pairs (60 VGPRs)
    f32x2 wr0[NRBF / 2], wr1[NRBF / 2], wr2[NRBF / 2];
#pragma unroll
    for (int k = 0; k < NRBF / 2; k++) {
        wr0[k] = (f32x2){Wr[(2 * k) * 384 + f], Wr[(2 * k + 1) * 384 + f]};
        wr1[k] = (f32x2){Wr[(2 * k) * 384 + 128 + f], Wr[(2 * k + 1) * 384 + 128 + f]};
        wr2[k] = (f32x2){Wr[(2 * k) * 384 + 256 + f], Wr[(2 * k + 1) * 384 + 256 + f]};
    }
    float bb0 = br[f], bb1 = br[128 + f], bb2 = br[256 + f];

    __shared__ float4 pay[16];
    __shared__ __align__(16) float rbfL[16][NRBF];

    for (int n = 0; n < NPB; n++) {
        int j = blockIdx.x * NPB + n;
        float sum1 = 0.f, sum2 = 0.f, sd0 = 0.f, sd1 = 0.f, sd2 = 0.f;
        int beg = offsets[j], end = offsets[j + 1];

        for (int base = beg; base < end; base += 16) {
            int cnt = min(16, end - base);
            __syncthreads();  // protect prev chunk's LDS reads
            if (f < cnt) pay[f] = payload[base + f];
            __syncthreads();
            for (int item = f; item < cnt * NRBF; item += 128) {
                int ec = item / NRBF, k = item - ec * NRBF;
                float nrm = pay[ec].w;
                float nc = fmaxf(nrm, FEPS);
                float sv = __sinf((float)(k + 1) * PIC * nc) / (nc + FEPS);
                rbfL[ec][k] = fminf(fmaxf(sv, -1.f), 1.f);
            }
            __syncthreads();
            for (int ec = 0; ec < cnt; ec++) {
                const f32x2* rb = (const f32x2*)(&rbfL[ec][0]);
                f32x2 d0 = (f32x2)(0.0f), d1 = (f32x2)(0.0f), d2 = (f32x2)(0.0f);
#pragma unroll
                for (int k = 0; k < NRBF / 2; k++) {
                    f32x2 rv = rb[k];
                    d0 = __builtin_elementwise_fma(rv, wr0[k], d0);
                    d1 = __builtin_elementwise_fma(rv, wr1[k], d1);
                    d2 = __builtin_elementwise_fma(rv, wr2[k], d2);
                }
                float a0 = bb0 + d0.x + d0.y;
                float a1 = bb1 + d1.x + d1.y;
                float a2 = bb2 + d2.x + d2.y;
                float w0 = 0.5f * (__cosf(PIC * a0) + 1.f); if (!(a0 < FCUT)) w0 = 0.f;
                float w1 = 0.5f * (__cosf(PIC * a1) + 1.f); if (!(a1 < FCUT)) w1 = 0.f;
                float w2 = 0.5f * (__cosf(PIC * a2) + 1.f); if (!(a2 < FCUT)) w2 = 0.f;
                sum1 += w0;
                sum2 += w1;
                float4 p = pay[ec];
                sd0 = fmaf(w2, p.x, sd0);
                sd1 = fmaf(w2, p.y, sd1);
                sd2 = fmaf(w2, p.z, sd2);
            }
        }

        float p1 = phi[(size_t)j * 384 + f];
        float p2 = phi[(size_t)j * 384 + 128 + f];
        float p3 = phi[(size_t)j * 384 + 256 + f];
        ds[(size_t)j * NF + f] = p2 * sum2;
        float c1 = p1 * sum1;
        size_t vb = ((size_t)j * NF + f) * 3;
        dv[vb + 0] = fmaf(v[vb + 0], c1, p3 * sd0);
        dv[vb + 1] = fmaf(v[vb + 1], c1, p3 * sd1);
        dv[vb + 2] = fmaf(v[vb + 2], c1, p3 * sd2);
    }
}

extern "C" void kernel_launch(void* const* d_in, const int* in_sizes, int n_in,
                              void* d_out, int out_size, void* d_ws, size_t ws_size,
                              hipStream_t stream) {
    const float* v  = (const float*)d_in[0];
    const float* s  = (const float*)d_in[1];
    const float* r  = (const float*)d_in[2];
    const float* W1 = (const float*)d_in[3];
    const float* b1 = (const float*)d_in[4];
    const float* W2 = (const float*)d_in[5];
    const float* b2 = (const float*)d_in[6];
    const float* Wr = (const float*)d_in[7];
    const float* br = (const float*)d_in[8];

    float* dv = (float*)d_out;                    // NND*NF*3
    float* ds = dv + (size_t)NND * NF * 3;        // NND*NF

    char* ws = (char*)d_ws;
    int* offsets = (int*)ws;                                   // 80128 B slot
    int* cursor  = (int*)(ws + 80128);                         // 80128 B slot
    float* bufA  = (float*)(ws + 160256);                      // 10,240,000 B (h, then payload)
    float* phi   = (float*)(ws + 160256 + 10240000);           // 30,720,000 B

    // 1. CSR build: histogram -> scan
    hipMemsetAsync(cursor, 0, NND * sizeof(int), stream);
    hist_k<<<(NE + 255) / 256, 256, 0, stream>>>(r, cursor);
    scan_k<<<1, 1024, 0, stream>>>(cursor, offsets);

    // 2. node MLP: h = silu(s@W1+b1); phi = h@W2+b2   (h lives in bufA)
    int nodeBlocks = (NND + 63) / 64;  // 313
    gemm_h_k<<<nodeBlocks, 256, 0, stream>>>(s, W1, b1, bufA);
    gemm_phi_k<<<dim3(nodeBlocks, 3), 256, 0, stream>>>(bufA, W2, b2, phi);

    // 3. scatter edges into CSR order (bufA reused as payload; stream-ordered after gemm_phi reads h)
    scatter_k<<<(NE + 255) / 256, 256, 0, stream>>>(r, cursor, (float4*)bufA);

    // 4. per-node reduction + outputs
    reduce_k<<<NND / NPB, 128, 0, stream>>>(offsets, (const float4*)bufA, phi, v, Wr, br, dv, ds);
}

// Round 3
// 197.052 us; speedup vs baseline: 1.3422x; 1.3422x over previous
//
#include <hip/hip_runtime.h>
#include <math.h>

#define NND 20000
#define NE  320000
#define NF  128
#define NRBF 20

typedef float f32x2 __attribute__((ext_vector_type(2)));
typedef float f32x4 __attribute__((ext_vector_type(4)));
typedef short bf16x8 __attribute__((ext_vector_type(8)));

static constexpr float FCUT = 5.0f;
static constexpr float FEPS = 1e-8f;
static constexpr float PIC  = 3.14159265358979323846f / 5.0f;  // pi / CUTOFF

__device__ __forceinline__ unsigned short f2bf(float x) {
    unsigned int u = __builtin_bit_cast(unsigned int, x);
    u += 0x7FFFu + ((u >> 16) & 1u);   // round-to-nearest-even
    return (unsigned short)(u >> 16);
}

// ---------------- histogram of destination nodes ----------------
__global__ __launch_bounds__(256) void hist_k(const float* __restrict__ r,
                                              int* __restrict__ counts) {
    int e = blockIdx.x * 256 + threadIdx.x;
    if (e < NE) {
        int j = (int)r[(size_t)e * 5 + 1];
        atomicAdd(&counts[j], 1);
    }
}

// ---------------- exclusive scan (20000 elems, 1 block) ----------------
__global__ __launch_bounds__(1024) void scan_k(int* counts_cursor,
                                               int* offsets) {
    __shared__ int part[1024];
    const int CH = 20;
    int t = threadIdx.x;
    int base = t * CH;
    int loc[CH];
    int sum = 0;
#pragma unroll
    for (int i = 0; i < CH; i++) {
        int idx = base + i;
        int c = (idx < NND) ? counts_cursor[idx] : 0;
        loc[i] = sum;
        sum += c;
    }
    part[t] = sum;
    __syncthreads();
    for (int off = 1; off < 1024; off <<= 1) {
        int val = (t >= off) ? part[t - off] : 0;
        __syncthreads();
        part[t] += val;
        __syncthreads();
    }
    int excl = part[t] - sum;
#pragma unroll
    for (int i = 0; i < CH; i++) {
        int idx = base + i;
        if (idx < NND) {
            int o = excl + loc[i];
            offsets[idx] = o;
            counts_cursor[idx] = o;
        }
    }
    if (t == 1023) offsets[NND] = part[1023];
}

// ---------------- scatter edges into CSR order, precompute dir/norm ----------------
__global__ __launch_bounds__(256) void scatter_k(const float* __restrict__ r,
                                                 int* __restrict__ cursor,
                                                 float4* __restrict__ payload) {
    int e = blockIdx.x * 256 + threadIdx.x;
    if (e >= NE) return;
    const float* re = r + (size_t)e * 5;
    int j = (int)re[1];
    float x = re[2], y = re[3], z = re[4];
    float nrm = sqrtf(x * x + y * y + z * z);
    float inv = 1.0f / ((nrm + FEPS) * (nrm + FEPS));
    int pos = atomicAdd(&cursor[j], 1);
    payload[pos] = make_float4(x * inv, y * inv, z * inv, nrm);
}

// ---------------- pack W (row-major KxN, fp32) into per-lane-contiguous bf16 B-fragments ----
// frag id fid = nch*256 + kk*64 + lane ; elem j: B[k0+j][col], k0 = kk*32+(lane>>4)*8,
// col = nch*16 + (lane&15)
__global__ __launch_bounds__(256) void pack_k(const float* __restrict__ W, int ncols,
                                              int nfrag, unsigned short* __restrict__ out) {
    int fid = blockIdx.x * 256 + threadIdx.x;
    if (fid >= nfrag) return;
    int lane = fid & 63;
    int kk = (fid >> 6) & 3;
    int nch = fid >> 8;
    int col = nch * 16 + (lane & 15);
    int k0 = kk * 32 + ((lane >> 4) * 8);
    unsigned short* o = out + (size_t)fid * 8;
#pragma unroll
    for (int j = 0; j < 8; j++) o[j] = f2bf(W[(size_t)(k0 + j) * ncols + col]);
}

// ---------------- h = silu(s @ W1 + b1), bf16 out, MFMA ----------------
// block = 4 waves, 64 nodes; each wave: 16-node M-tile x 128 cols
__global__ __launch_bounds__(256) void mlp1_k(const float* __restrict__ s,
                                              const unsigned short* __restrict__ Wp,
                                              const float* __restrict__ b1,
                                              unsigned short* __restrict__ h) {
    int lane = threadIdx.x & 63, wave = threadIdx.x >> 6;
    int node0 = blockIdx.x * 64 + wave * 16;
    int arow = lane & 15, kgrp = lane >> 4;
    int anode = node0 + arow; if (anode > NND - 1) anode = NND - 1;
    const float* ap = s + (size_t)anode * NF + kgrp * 8;
    bf16x8 afrag[4];
#pragma unroll
    for (int kk = 0; kk < 4; kk++) {
        float4 x0 = *(const float4*)(ap + kk * 32);
        float4 x1 = *(const float4*)(ap + kk * 32 + 4);
        union { unsigned short u[8]; bf16x8 v; } c;
        c.u[0] = f2bf(x0.x); c.u[1] = f2bf(x0.y); c.u[2] = f2bf(x0.z); c.u[3] = f2bf(x0.w);
        c.u[4] = f2bf(x1.x); c.u[5] = f2bf(x1.y); c.u[6] = f2bf(x1.z); c.u[7] = f2bf(x1.w);
        afrag[kk] = c.v;
    }
    f32x4 acc[8];
#pragma unroll
    for (int n = 0; n < 8; n++) acc[n] = (f32x4)(0.0f);
    const bf16x8* W8 = (const bf16x8*)Wp;
#pragma unroll
    for (int nch = 0; nch < 8; nch++)
#pragma unroll
        for (int kk = 0; kk < 4; kk++)
            acc[nch] = __builtin_amdgcn_mfma_f32_16x16x32_bf16(
                afrag[kk], W8[(nch * 4 + kk) * 64 + lane], acc[nch], 0, 0, 0);
#pragma unroll
    for (int nch = 0; nch < 8; nch++) {
        int col = nch * 16 + arow;
        float bb = b1[col];
#pragma unroll
        for (int rg = 0; rg < 4; rg++) {
            int noder = node0 + kgrp * 4 + rg;
            if (noder < NND) {
                float x = acc[nch][rg] + bb;
                float y = x / (1.0f + __expf(-x));
                h[(size_t)noder * NF + col] = f2bf(y);
            }
        }
    }
}

// ---------------- phi = h @ W2 + b2 (fp32 out), MFMA; grid.y = col chunk of 128 ----
__global__ __launch_bounds__(256) void mlp2_k(const unsigned short* __restrict__ h,
                                              const unsigned short* __restrict__ Wp,
                                              const float* __restrict__ b2,
                                              float* __restrict__ phi) {
    int lane = threadIdx.x & 63, wave = threadIdx.x >> 6;
    int node0 = blockIdx.x * 64 + wave * 16;
    int c = blockIdx.y;  // 0..2
    int arow = lane & 15, kgrp = lane >> 4;
    int anode = node0 + arow; if (anode > NND - 1) anode = NND - 1;
    const unsigned short* ap = h + (size_t)anode * NF + kgrp * 8;
    bf16x8 afrag[4];
#pragma unroll
    for (int kk = 0; kk < 4; kk++) afrag[kk] = *(const bf16x8*)(ap + kk * 32);
    f32x4 acc[8];
#pragma unroll
    for (int n = 0; n < 8; n++) acc[n] = (f32x4)(0.0f);
    const bf16x8* W8 = (const bf16x8*)Wp;
#pragma unroll
    for (int nch = 0; nch < 8; nch++)
#pragma unroll
        for (int kk = 0; kk < 4; kk++)
            acc[nch] = __builtin_amdgcn_mfma_f32_16x16x32_bf16(
                afrag[kk], W8[((c * 8 + nch) * 4 + kk) * 64 + lane], acc[nch], 0, 0, 0);
#pragma unroll
    for (int nch = 0; nch < 8; nch++) {
        int col = c * NF + nch * 16 + arow;
        float bb = b2[col];
#pragma unroll
        for (int rg = 0; rg < 4; rg++) {
            int noder = node0 + kgrp * 4 + rg;
            if (noder < NND) phi[(size_t)noder * 384 + col] = acc[nch][rg] + bb;
        }
    }
}

// ---------------- per-node reduction over its edges + output write ----------------
__global__ __launch_bounds__(128) void reduce_k(const int* __restrict__ offsets,
                                                const float4* __restrict__ payload,
                                                const float* __restrict__ phi,
                                                const float* __restrict__ v,
                                                const float* __restrict__ Wr,
                                                const float* __restrict__ br,
                                                float* __restrict__ dv,
                                                float* __restrict__ ds) {
    int j = blockIdx.x;
    int f = threadIdx.x;
    f32x2 wr0[NRBF / 2], wr1[NRBF / 2], wr2[NRBF / 2];
#pragma unroll
    for (int k = 0; k < NRBF / 2; k++) {
        wr0[k] = (f32x2){Wr[(2 * k) * 384 + f], Wr[(2 * k + 1) * 384 + f]};
        wr1[k] = (f32x2){Wr[(2 * k) * 384 + 128 + f], Wr[(2 * k + 1) * 384 + 128 + f]};
        wr2[k] = (f32x2){Wr[(2 * k) * 384 + 256 + f], Wr[(2 * k + 1) * 384 + 256 + f]};
    }
    float bb0 = br[f], bb1 = br[128 + f], bb2 = br[256 + f];

    float sum1 = 0.f, sum2 = 0.f, sd0 = 0.f, sd1 = 0.f, sd2 = 0.f;
    int beg = offsets[j], end = offsets[j + 1];

    __shared__ float4 pay[16];
    __shared__ __align__(16) float rbfL[16][NRBF];

    for (int base = beg; base < end; base += 16) {
        int cnt = min(16, end - base);
        __syncthreads();  // protect prev chunk's LDS reads
        if (f < cnt) pay[f] = payload[base + f];
        __syncthreads();
        for (int item = f; item < cnt * NRBF; item += 128) {
            int ec = item / NRBF, k = item - ec * NRBF;
            float nrm = pay[ec].w;
            float nc = fmaxf(nrm, FEPS);
            float sv = __sinf((float)(k + 1) * PIC * nc) / (nc + FEPS);
            rbfL[ec][k] = fminf(fmaxf(sv, -1.f), 1.f);
        }
        __syncthreads();
        for (int ec = 0; ec < cnt; ec++) {
            const f32x2* rb = (const f32x2*)(&rbfL[ec][0]);
            f32x2 d0 = (f32x2)(0.0f), d1 = (f32x2)(0.0f), d2 = (f32x2)(0.0f);
#pragma unroll
            for (int k = 0; k < NRBF / 2; k++) {
                f32x2 rv = rb[k];
                d0 = __builtin_elementwise_fma(rv, wr0[k], d0);
                d1 = __builtin_elementwise_fma(rv, wr1[k], d1);
                d2 = __builtin_elementwise_fma(rv, wr2[k], d2);
            }
            float a0 = bb0 + d0.x + d0.y;
            float a1 = bb1 + d1.x + d1.y;
            float a2 = bb2 + d2.x + d2.y;
            float w0 = 0.5f * (__cosf(PIC * a0) + 1.f); if (!(a0 < FCUT)) w0 = 0.f;
            float w1 = 0.5f * (__cosf(PIC * a1) + 1.f); if (!(a1 < FCUT)) w1 = 0.f;
            float w2 = 0.5f * (__cosf(PIC * a2) + 1.f); if (!(a2 < FCUT)) w2 = 0.f;
            sum1 += w0;
            sum2 += w1;
            float4 p = pay[ec];
            sd0 = fmaf(w2, p.x, sd0);
            sd1 = fmaf(w2, p.y, sd1);
            sd2 = fmaf(w2, p.z, sd2);
        }
    }

    float p1 = phi[(size_t)j * 384 + f];
    float p2 = phi[(size_t)j * 384 + 128 + f];
    float p3 = phi[(size_t)j * 384 + 256 + f];
    ds[(size_t)j * NF + f] = p2 * sum2;
    float c1 = p1 * sum1;
    size_t vb = ((size_t)j * NF + f) * 3;
    dv[vb + 0] = fmaf(v[vb + 0], c1, p3 * sd0);
    dv[vb + 1] = fmaf(v[vb + 1], c1, p3 * sd1);
    dv[vb + 2] = fmaf(v[vb + 2], c1, p3 * sd2);
}

extern "C" void kernel_launch(void* const* d_in, const int* in_sizes, int n_in,
                              void* d_out, int out_size, void* d_ws, size_t ws_size,
                              hipStream_t stream) {
    const float* v  = (const float*)d_in[0];
    const float* s  = (const float*)d_in[1];
    const float* r  = (const float*)d_in[2];
    const float* W1 = (const float*)d_in[3];
    const float* b1 = (const float*)d_in[4];
    const float* W2 = (const float*)d_in[5];
    const float* b2 = (const float*)d_in[6];
    const float* Wr = (const float*)d_in[7];
    const float* br = (const float*)d_in[8];

    float* dv = (float*)d_out;                    // NND*NF*3
    float* ds = dv + (size_t)NND * NF * 3;        // NND*NF

    char* ws = (char*)d_ws;
    int* offsets            = (int*)ws;                         // 80,128 B
    int* cursor             = (int*)(ws + 80128);               // 80,128 B
    float* payload          = (float*)(ws + 160256);            // 5,120,000 B
    unsigned short* hbuf    = (unsigned short*)(ws + 5280256);  // 5,120,000 B
    unsigned short* Wp1     = (unsigned short*)(ws + 10400256); //    32,768 B
    unsigned short* Wp2     = (unsigned short*)(ws + 10433024); //    98,304 B
    float* phi              = (float*)(ws + 10531328);          // 30,720,000 B

    // 1. CSR build: histogram -> scan -> scatter (payload independent of MLP bufs)
    hipMemsetAsync(cursor, 0, NND * sizeof(int), stream);
    hist_k<<<(NE + 255) / 256, 256, 0, stream>>>(r, cursor);
    scan_k<<<1, 1024, 0, stream>>>(cursor, offsets);
    scatter_k<<<(NE + 255) / 256, 256, 0, stream>>>(r, cursor, (float4*)payload);

    // 2. pack weights into bf16 B-fragments
    pack_k<<<8, 256, 0, stream>>>(W1, 128, 2048, Wp1);
    pack_k<<<24, 256, 0, stream>>>(W2, 384, 6144, Wp2);

    // 3. node MLP via MFMA
    int nodeBlocks = (NND + 63) / 64;  // 313
    mlp1_k<<<nodeBlocks, 256, 0, stream>>>(s, Wp1, b1, hbuf);
    mlp2_k<<<dim3(nodeBlocks, 3), 256, 0, stream>>>(hbuf, Wp2, b2, phi);

    // 4. per-node reduction + outputs
    reduce_k<<<NND, 128, 0, stream>>>(offsets, (const float4*)payload, phi, v, Wr, br, dv, ds);
}

// Round 4
// 193.001 us; speedup vs baseline: 1.3703x; 1.0210x over previous
//
#include <hip/hip_runtime.h>
#include <math.h>

#define NND 20000
#define NE  320000
#define NF  128
#define NRBF 20

typedef float f32x2 __attribute__((ext_vector_type(2)));
typedef float f32x4 __attribute__((ext_vector_type(4)));
typedef short bf16x8 __attribute__((ext_vector_type(8)));

static constexpr float FCUT = 5.0f;
static constexpr float FEPS = 1e-8f;
static constexpr float PIC  = 3.14159265358979323846f / 5.0f;  // pi / CUTOFF

__device__ __forceinline__ unsigned short f2bf(float x) {
    unsigned int u = __builtin_bit_cast(unsigned int, x);
    u += 0x7FFFu + ((u >> 16) & 1u);   // round-to-nearest-even
    return (unsigned short)(u >> 16);
}

// ---------------- histogram of destination nodes ----------------
__global__ __launch_bounds__(256) void hist_k(const float* __restrict__ r,
                                              int* __restrict__ counts) {
    int e = blockIdx.x * 256 + threadIdx.x;
    if (e < NE) {
        int j = (int)r[(size_t)e * 5 + 1];
        atomicAdd(&counts[j], 1);
    }
}

// ---------------- exclusive scan (20000 elems, 1 block) ----------------
__global__ __launch_bounds__(1024) void scan_k(int* counts_cursor,
                                               int* offsets) {
    __shared__ int part[1024];
    const int CH = 20;
    int t = threadIdx.x;
    int base = t * CH;
    int loc[CH];
    int sum = 0;
#pragma unroll
    for (int i = 0; i < CH; i++) {
        int idx = base + i;
        int c = (idx < NND) ? counts_cursor[idx] : 0;
        loc[i] = sum;
        sum += c;
    }
    part[t] = sum;
    __syncthreads();
    for (int off = 1; off < 1024; off <<= 1) {
        int val = (t >= off) ? part[t - off] : 0;
        __syncthreads();
        part[t] += val;
        __syncthreads();
    }
    int excl = part[t] - sum;
#pragma unroll
    for (int i = 0; i < CH; i++) {
        int idx = base + i;
        if (idx < NND) {
            int o = excl + loc[i];
            offsets[idx] = o;
            counts_cursor[idx] = o;
        }
    }
    if (t == 1023) offsets[NND] = part[1023];
}

// ---------------- scatter edges into CSR order, precompute dir/norm ----------------
__global__ __launch_bounds__(256) void scatter_k(const float* __restrict__ r,
                                                 int* __restrict__ cursor,
                                                 float4* __restrict__ payload) {
    int e = blockIdx.x * 256 + threadIdx.x;
    if (e >= NE) return;
    const float* re = r + (size_t)e * 5;
    int j = (int)re[1];
    float x = re[2], y = re[3], z = re[4];
    float nrm = sqrtf(x * x + y * y + z * z);
    float inv = 1.0f / ((nrm + FEPS) * (nrm + FEPS));
    int pos = atomicAdd(&cursor[j], 1);
    payload[pos] = make_float4(x * inv, y * inv, z * inv, nrm);
}

// ---------------- pack W (row-major KxN, fp32) into per-lane-contiguous bf16 B-fragments ----
__global__ __launch_bounds__(256) void pack_k(const float* __restrict__ W, int ncols,
                                              int nfrag, unsigned short* __restrict__ out) {
    int fid = blockIdx.x * 256 + threadIdx.x;
    if (fid >= nfrag) return;
    int lane = fid & 63;
    int kk = (fid >> 6) & 3;
    int nch = fid >> 8;
    int col = nch * 16 + (lane & 15);
    int k0 = kk * 32 + ((lane >> 4) * 8);
    unsigned short* o = out + (size_t)fid * 8;
#pragma unroll
    for (int j = 0; j < 8; j++) o[j] = f2bf(W[(size_t)(k0 + j) * ncols + col]);
}

// ---------------- pack Wr (20x384) + br into bf16 B-frags, K padded to 32 ----------------
// frag ft = feature tile 0..23; lane: col = ft*16+(lane&15), k = (lane>>4)*8 + j
// k<20 -> Wr[k][col]; k==20 -> br[col]; else 0
__global__ __launch_bounds__(256) void pack_wr_k(const float* __restrict__ Wr,
                                                 const float* __restrict__ br,
                                                 unsigned short* __restrict__ out) {
    int fid = blockIdx.x * 256 + threadIdx.x;
    if (fid >= 24 * 64) return;
    int lane = fid & 63, ft = fid >> 6;
    int col = ft * 16 + (lane & 15);
    int k0 = (lane >> 4) * 8;
    unsigned short* o = out + (size_t)fid * 8;
#pragma unroll
    for (int j = 0; j < 8; j++) {
        int k = k0 + j;
        float val = (k < NRBF) ? Wr[(size_t)k * 384 + col] : ((k == NRBF) ? br[col] : 0.0f);
        o[j] = f2bf(val);
    }
}

// ---------------- h = silu(s @ W1 + b1), bf16 out, MFMA ----------------
__global__ __launch_bounds__(256) void mlp1_k(const float* __restrict__ s,
                                              const unsigned short* __restrict__ Wp,
                                              const float* __restrict__ b1,
                                              unsigned short* __restrict__ h) {
    int lane = threadIdx.x & 63, wave = threadIdx.x >> 6;
    int node0 = blockIdx.x * 64 + wave * 16;
    int arow = lane & 15, kgrp = lane >> 4;
    int anode = node0 + arow; if (anode > NND - 1) anode = NND - 1;
    const float* ap = s + (size_t)anode * NF + kgrp * 8;
    bf16x8 afrag[4];
#pragma unroll
    for (int kk = 0; kk < 4; kk++) {
        float4 x0 = *(const float4*)(ap + kk * 32);
        float4 x1 = *(const float4*)(ap + kk * 32 + 4);
        union { unsigned short u[8]; bf16x8 v; } c;
        c.u[0] = f2bf(x0.x); c.u[1] = f2bf(x0.y); c.u[2] = f2bf(x0.z); c.u[3] = f2bf(x0.w);
        c.u[4] = f2bf(x1.x); c.u[5] = f2bf(x1.y); c.u[6] = f2bf(x1.z); c.u[7] = f2bf(x1.w);
        afrag[kk] = c.v;
    }
    f32x4 acc[8];
#pragma unroll
    for (int n = 0; n < 8; n++) acc[n] = (f32x4)(0.0f);
    const bf16x8* W8 = (const bf16x8*)Wp;
#pragma unroll
    for (int nch = 0; nch < 8; nch++)
#pragma unroll
        for (int kk = 0; kk < 4; kk++)
            acc[nch] = __builtin_amdgcn_mfma_f32_16x16x32_bf16(
                afrag[kk], W8[(nch * 4 + kk) * 64 + lane], acc[nch], 0, 0, 0);
#pragma unroll
    for (int nch = 0; nch < 8; nch++) {
        int col = nch * 16 + arow;
        float bb = b1[col];
#pragma unroll
        for (int rg = 0; rg < 4; rg++) {
            int noder = node0 + kgrp * 4 + rg;
            if (noder < NND) {
                float x = acc[nch][rg] + bb;
                float y = x / (1.0f + __expf(-x));
                h[(size_t)noder * NF + col] = f2bf(y);
            }
        }
    }
}

// ---------------- phi = h @ W2 + b2 (fp32 out), MFMA ----------------
__global__ __launch_bounds__(256) void mlp2_k(const unsigned short* __restrict__ h,
                                              const unsigned short* __restrict__ Wp,
                                              const float* __restrict__ b2,
                                              float* __restrict__ phi) {
    int lane = threadIdx.x & 63, wave = threadIdx.x >> 6;
    int node0 = blockIdx.x * 64 + wave * 16;
    int c = blockIdx.y;  // 0..2
    int arow = lane & 15, kgrp = lane >> 4;
    int anode = node0 + arow; if (anode > NND - 1) anode = NND - 1;
    const unsigned short* ap = h + (size_t)anode * NF + kgrp * 8;
    bf16x8 afrag[4];
#pragma unroll
    for (int kk = 0; kk < 4; kk++) afrag[kk] = *(const bf16x8*)(ap + kk * 32);
    f32x4 acc[8];
#pragma unroll
    for (int n = 0; n < 8; n++) acc[n] = (f32x4)(0.0f);
    const bf16x8* W8 = (const bf16x8*)Wp;
#pragma unroll
    for (int nch = 0; nch < 8; nch++)
#pragma unroll
        for (int kk = 0; kk < 4; kk++)
            acc[nch] = __builtin_amdgcn_mfma_f32_16x16x32_bf16(
                afrag[kk], W8[((c * 8 + nch) * 4 + kk) * 64 + lane], acc[nch], 0, 0, 0);
#pragma unroll
    for (int nch = 0; nch < 8; nch++) {
        int col = c * NF + nch * 16 + arow;
        float bb = b2[col];
#pragma unroll
        for (int rg = 0; rg < 4; rg++) {
            int noder = node0 + kgrp * 4 + rg;
            if (noder < NND) phi[(size_t)noder * 384 + col] = acc[nch][rg] + bb;
        }
    }
}

// ---------------- per-node edge reduction via MFMA ----------------
// One wave per node (grid-stride). Virtual 16-edge tiles; A = rbf (built in-register),
// B = packed Wr frags (persistent in 96 VGPRs); nonlinearity+masked reduce on D frags.
__global__ __launch_bounds__(256) void reduce2_k(const int* __restrict__ offsets,
                                                 const float4* __restrict__ payload,
                                                 const float* __restrict__ phi,
                                                 const float* __restrict__ v,
                                                 const unsigned short* __restrict__ WrP,
                                                 float* __restrict__ dv,
                                                 float* __restrict__ ds) {
    int lane = threadIdx.x & 63;
    int la = lane & 15, kg = lane >> 4;
    int gw = blockIdx.x * 4 + (threadIdx.x >> 6);
    int nw = gridDim.x * 4;

    bf16x8 wrf[24];
#pragma unroll
    for (int ft = 0; ft < 24; ft++)
        wrf[ft] = *(const bf16x8*)(WrP + (size_t)((ft << 6) + lane) * 8);

    for (int j = gw; j < NND; j += nw) {
        int beg = offsets[j], end = offsets[j + 1];
        float a0[8], a1[8], sdx[8], sdy[8], sdz[8];
#pragma unroll
        for (int i = 0; i < 8; i++) { a0[i] = 0.f; a1[i] = 0.f; sdx[i] = 0.f; sdy[i] = 0.f; sdz[i] = 0.f; }

        for (int base = beg; base < end; base += 16) {
            int cnt = end - base; if (cnt > 16) cnt = 16;
            float4 p = payload[base + (la < cnt ? la : cnt - 1)];
            // --- build A fragment: row = la (edge), k = kg*8 + j2 ---
            float nc = fmaxf(p.w, FEPS);
            float invd = 1.0f / (nc + FEPS);
            union { unsigned short u[8]; bf16x8 v8; } af;
#pragma unroll
            for (int j2 = 0; j2 < 8; j2++) {
                int k = kg * 8 + j2;
                float sv = __sinf((float)(k + 1) * PIC * nc) * invd;
                sv = fminf(fmaxf(sv, -1.f), 1.f);
                unsigned short b = f2bf(sv);
                af.u[j2] = (k < NRBF) ? b : (unsigned short)((k == NRBF) ? 0x3F80 : 0);
            }
            // --- masks and dirs for my D-rows e = kg*4+rr ---
            float mk[4], dx[4], dy[4], dz[4];
#pragma unroll
            for (int rr = 0; rr < 4; rr++) {
                int er = kg * 4 + rr;
                mk[rr] = (er < cnt) ? 1.0f : 0.0f;
                dx[rr] = __shfl(p.x, er);
                dy[rr] = __shfl(p.y, er);
                dz[rr] = __shfl(p.z, er);
            }
            // --- 24 feature tiles ---
#pragma unroll
            for (int ft = 0; ft < 24; ft++) {
                f32x4 d = __builtin_amdgcn_mfma_f32_16x16x32_bf16(af.v8, wrf[ft], (f32x4)(0.0f), 0, 0, 0);
#pragma unroll
                for (int rr = 0; rr < 4; rr++) {
                    float a = d[rr];
                    float w = 0.5f * (__cosf(PIC * a) + 1.0f);
                    w = (a < FCUT) ? w : 0.0f;
                    w *= mk[rr];
                    if (ft < 8)       a0[ft] += w;
                    else if (ft < 16) a1[ft - 8] += w;
                    else {
                        sdx[ft - 16] = fmaf(w, dx[rr], sdx[ft - 16]);
                        sdy[ft - 16] = fmaf(w, dy[rr], sdy[ft - 16]);
                        sdz[ft - 16] = fmaf(w, dz[rr], sdz[ft - 16]);
                    }
                }
            }
        }
        // --- butterfly reduce across the 4 kg groups (lanes la, la+16, la+32, la+48) ---
#pragma unroll
        for (int i = 0; i < 8; i++) {
            a0[i] += __shfl_xor(a0[i], 16);  a0[i] += __shfl_xor(a0[i], 32);
            a1[i] += __shfl_xor(a1[i], 16);  a1[i] += __shfl_xor(a1[i], 32);
            sdx[i] += __shfl_xor(sdx[i], 16); sdx[i] += __shfl_xor(sdx[i], 32);
            sdy[i] += __shfl_xor(sdy[i], 16); sdy[i] += __shfl_xor(sdy[i], 32);
            sdz[i] += __shfl_xor(sdz[i], 16); sdz[i] += __shfl_xor(sdz[i], 32);
        }
        // --- epilogue: lane (kg,la) writes features f = ff*16+la for ff in {2kg, 2kg+1} ---
#pragma unroll
        for (int ff = 0; ff < 8; ff++) {
            if ((ff >> 1) == kg) {
                int f = ff * 16 + la;
                float p1 = phi[(size_t)j * 384 + f];
                float p2 = phi[(size_t)j * 384 + 128 + f];
                float p3 = phi[(size_t)j * 384 + 256 + f];
                ds[(size_t)j * NF + f] = p2 * a1[ff];
                float c1 = p1 * a0[ff];
                size_t vb = ((size_t)j * NF + f) * 3;
                dv[vb + 0] = fmaf(v[vb + 0], c1, p3 * sdx[ff]);
                dv[vb + 1] = fmaf(v[vb + 1], c1, p3 * sdy[ff]);
                dv[vb + 2] = fmaf(v[vb + 2], c1, p3 * sdz[ff]);
            }
        }
    }
}

extern "C" void kernel_launch(void* const* d_in, const int* in_sizes, int n_in,
                              void* d_out, int out_size, void* d_ws, size_t ws_size,
                              hipStream_t stream) {
    const float* v  = (const float*)d_in[0];
    const float* s  = (const float*)d_in[1];
    const float* r  = (const float*)d_in[2];
    const float* W1 = (const float*)d_in[3];
    const float* b1 = (const float*)d_in[4];
    const float* W2 = (const float*)d_in[5];
    const float* b2 = (const float*)d_in[6];
    const float* Wr = (const float*)d_in[7];
    const float* br = (const float*)d_in[8];

    float* dv = (float*)d_out;                    // NND*NF*3
    float* ds = dv + (size_t)NND * NF * 3;        // NND*NF

    char* ws = (char*)d_ws;
    int* offsets            = (int*)ws;                         // 80,128 B
    int* cursor             = (int*)(ws + 80128);               // 80,128 B
    float* payload          = (float*)(ws + 160256);            // 5,120,000 B
    unsigned short* hbuf    = (unsigned short*)(ws + 5280256);  // 5,120,000 B
    unsigned short* Wp1     = (unsigned short*)(ws + 10400256); //    32,768 B
    unsigned short* Wp2     = (unsigned short*)(ws + 10433024); //    98,304 B
    unsigned short* WrP     = (unsigned short*)(ws + 10531328); //    24,576 B
    float* phi              = (float*)(ws + 10555904);          // 30,720,000 B

    // 1. CSR build: histogram -> scan -> scatter
    hipMemsetAsync(cursor, 0, NND * sizeof(int), stream);
    hist_k<<<(NE + 255) / 256, 256, 0, stream>>>(r, cursor);
    scan_k<<<1, 1024, 0, stream>>>(cursor, offsets);
    scatter_k<<<(NE + 255) / 256, 256, 0, stream>>>(r, cursor, (float4*)payload);

    // 2. pack weights into bf16 B-fragments
    pack_k<<<8, 256, 0, stream>>>(W1, 128, 2048, Wp1);
    pack_k<<<24, 256, 0, stream>>>(W2, 384, 6144, Wp2);
    pack_wr_k<<<6, 256, 0, stream>>>(Wr, br, WrP);

    // 3. node MLP via MFMA
    int nodeBlocks = (NND + 63) / 64;  // 313
    mlp1_k<<<nodeBlocks, 256, 0, stream>>>(s, Wp1, b1, hbuf);
    mlp2_k<<<dim3(nodeBlocks, 3), 256, 0, stream>>>(hbuf, Wp2, b2, phi);

    // 4. per-node edge reduction via MFMA + outputs
    reduce2_k<<<512, 256, 0, stream>>>(offsets, (const float4*)payload, phi, v, WrP, dv, ds);
}

// Round 5
// 175.037 us; speedup vs baseline: 1.5110x; 1.1026x over previous
//
#include <hip/hip_runtime.h>
#include <math.h>

#define NND 20000
#define NE  320000
#define NF  128
#define NRBF 20

typedef float f32x2 __attribute__((ext_vector_type(2)));
typedef float f32x4 __attribute__((ext_vector_type(4)));
typedef short bf16x8 __attribute__((ext_vector_type(8)));

static constexpr float FCUT = 5.0f;
static constexpr float FEPS = 1e-8f;
static constexpr float PIC  = 3.14159265358979323846f / 5.0f;  // pi / CUTOFF

__device__ __forceinline__ unsigned short f2bf(float x) {
    unsigned int u = __builtin_bit_cast(unsigned int, x);
    u += 0x7FFFu + ((u >> 16) & 1u);   // round-to-nearest-even
    return (unsigned short)(u >> 16);
}

// ---------------- histogram of destination nodes ----------------
__global__ __launch_bounds__(256) void hist_k(const float* __restrict__ r,
                                              int* __restrict__ counts) {
    int e = blockIdx.x * 256 + threadIdx.x;
    if (e < NE) {
        int j = (int)r[(size_t)e * 5 + 1];
        atomicAdd(&counts[j], 1);
    }
}

// ---------------- exclusive scan (20000 elems, 1 block) ----------------
__global__ __launch_bounds__(1024) void scan_k(int* counts_cursor,
                                               int* offsets) {
    __shared__ int part[1024];
    const int CH = 20;
    int t = threadIdx.x;
    int base = t * CH;
    int loc[CH];
    int sum = 0;
#pragma unroll
    for (int i = 0; i < CH; i++) {
        int idx = base + i;
        int c = (idx < NND) ? counts_cursor[idx] : 0;
        loc[i] = sum;
        sum += c;
    }
    part[t] = sum;
    __syncthreads();
    for (int off = 1; off < 1024; off <<= 1) {
        int val = (t >= off) ? part[t - off] : 0;
        __syncthreads();
        part[t] += val;
        __syncthreads();
    }
    int excl = part[t] - sum;
#pragma unroll
    for (int i = 0; i < CH; i++) {
        int idx = base + i;
        if (idx < NND) {
            int o = excl + loc[i];
            offsets[idx] = o;
            counts_cursor[idx] = o;
        }
    }
    if (t == 1023) offsets[NND] = part[1023];
}

// ---------------- scatter edges into CSR order, precompute dir/norm ----------------
__global__ __launch_bounds__(256) void scatter_k(const float* __restrict__ r,
                                                 int* __restrict__ cursor,
                                                 float4* __restrict__ payload) {
    int e = blockIdx.x * 256 + threadIdx.x;
    if (e >= NE) return;
    const float* re = r + (size_t)e * 5;
    int j = (int)re[1];
    float x = re[2], y = re[3], z = re[4];
    float nrm = sqrtf(x * x + y * y + z * z);
    float inv = 1.0f / ((nrm + FEPS) * (nrm + FEPS));
    int pos = atomicAdd(&cursor[j], 1);
    payload[pos] = make_float4(x * inv, y * inv, z * inv, nrm);
}

// ---------------- pack all weights into bf16 B-fragments (one kernel) ----------------
// fid < 2048          : W1 (128x128)
// fid < 2048+6144     : W2 (128x384)
// fid < 2048+6144+1536: Wr (20x384, K padded to 32 with br at k=20)
__global__ __launch_bounds__(256) void pack_all_k(const float* __restrict__ W1,
                                                  const float* __restrict__ W2,
                                                  const float* __restrict__ Wr,
                                                  const float* __restrict__ br,
                                                  unsigned short* __restrict__ Wp1,
                                                  unsigned short* __restrict__ Wp2,
                                                  unsigned short* __restrict__ WrP) {
    int fid = blockIdx.x * 256 + threadIdx.x;
    if (fid < 2048) {
        int lane = fid & 63, kk = (fid >> 6) & 3, nch = fid >> 8;
        int col = nch * 16 + (lane & 15);
        int k0 = kk * 32 + ((lane >> 4) * 8);
        unsigned short* o = Wp1 + (size_t)fid * 8;
#pragma unroll
        for (int j = 0; j < 8; j++) o[j] = f2bf(W1[(size_t)(k0 + j) * 128 + col]);
    } else if (fid < 2048 + 6144) {
        int f2 = fid - 2048;
        int lane = f2 & 63, kk = (f2 >> 6) & 3, nch = f2 >> 8;
        int col = nch * 16 + (lane & 15);
        int k0 = kk * 32 + ((lane >> 4) * 8);
        unsigned short* o = Wp2 + (size_t)f2 * 8;
#pragma unroll
        for (int j = 0; j < 8; j++) o[j] = f2bf(W2[(size_t)(k0 + j) * 384 + col]);
    } else if (fid < 2048 + 6144 + 1536) {
        int f3 = fid - 8192;
        int lane = f3 & 63, ft = f3 >> 6;
        int col = ft * 16 + (lane & 15);
        int k0 = (lane >> 4) * 8;
        unsigned short* o = WrP + (size_t)f3 * 8;
#pragma unroll
        for (int j = 0; j < 8; j++) {
            int k = k0 + j;
            float val = (k < NRBF) ? Wr[(size_t)k * 384 + col] : ((k == NRBF) ? br[col] : 0.0f);
            o[j] = f2bf(val);
        }
    }
}

// ---------------- h = silu(s @ W1 + b1), bf16 out, MFMA ----------------
__global__ __launch_bounds__(256) void mlp1_k(const float* __restrict__ s,
                                              const unsigned short* __restrict__ Wp,
                                              const float* __restrict__ b1,
                                              unsigned short* __restrict__ h) {
    int lane = threadIdx.x & 63, wave = threadIdx.x >> 6;
    int node0 = blockIdx.x * 64 + wave * 16;
    int arow = lane & 15, kgrp = lane >> 4;
    int anode = node0 + arow; if (anode > NND - 1) anode = NND - 1;
    const float* ap = s + (size_t)anode * NF + kgrp * 8;
    bf16x8 afrag[4];
#pragma unroll
    for (int kk = 0; kk < 4; kk++) {
        float4 x0 = *(const float4*)(ap + kk * 32);
        float4 x1 = *(const float4*)(ap + kk * 32 + 4);
        union { unsigned short u[8]; bf16x8 v; } c;
        c.u[0] = f2bf(x0.x); c.u[1] = f2bf(x0.y); c.u[2] = f2bf(x0.z); c.u[3] = f2bf(x0.w);
        c.u[4] = f2bf(x1.x); c.u[5] = f2bf(x1.y); c.u[6] = f2bf(x1.z); c.u[7] = f2bf(x1.w);
        afrag[kk] = c.v;
    }
    f32x4 acc[8];
#pragma unroll
    for (int n = 0; n < 8; n++) acc[n] = (f32x4)(0.0f);
    const bf16x8* W8 = (const bf16x8*)Wp;
#pragma unroll
    for (int nch = 0; nch < 8; nch++)
#pragma unroll
        for (int kk = 0; kk < 4; kk++)
            acc[nch] = __builtin_amdgcn_mfma_f32_16x16x32_bf16(
                afrag[kk], W8[(nch * 4 + kk) * 64 + lane], acc[nch], 0, 0, 0);
#pragma unroll
    for (int nch = 0; nch < 8; nch++) {
        int col = nch * 16 + arow;
        float bb = b1[col];
#pragma unroll
        for (int rg = 0; rg < 4; rg++) {
            int noder = node0 + kgrp * 4 + rg;
            if (noder < NND) {
                float x = acc[nch][rg] + bb;
                float y = x / (1.0f + __expf(-x));
                h[(size_t)noder * NF + col] = f2bf(y);
            }
        }
    }
}

// ---------------- phi = h @ W2 + b2 (fp32 out), MFMA ----------------
__global__ __launch_bounds__(256) void mlp2_k(const unsigned short* __restrict__ h,
                                              const unsigned short* __restrict__ Wp,
                                              const float* __restrict__ b2,
                                              float* __restrict__ phi) {
    int lane = threadIdx.x & 63, wave = threadIdx.x >> 6;
    int node0 = blockIdx.x * 64 + wave * 16;
    int c = blockIdx.y;  // 0..2
    int arow = lane & 15, kgrp = lane >> 4;
    int anode = node0 + arow; if (anode > NND - 1) anode = NND - 1;
    const unsigned short* ap = h + (size_t)anode * NF + kgrp * 8;
    bf16x8 afrag[4];
#pragma unroll
    for (int kk = 0; kk < 4; kk++) afrag[kk] = *(const bf16x8*)(ap + kk * 32);
    f32x4 acc[8];
#pragma unroll
    for (int n = 0; n < 8; n++) acc[n] = (f32x4)(0.0f);
    const bf16x8* W8 = (const bf16x8*)Wp;
#pragma unroll
    for (int nch = 0; nch < 8; nch++)
#pragma unroll
        for (int kk = 0; kk < 4; kk++)
            acc[nch] = __builtin_amdgcn_mfma_f32_16x16x32_bf16(
                afrag[kk], W8[((c * 8 + nch) * 4 + kk) * 64 + lane], acc[nch], 0, 0, 0);
#pragma unroll
    for (int nch = 0; nch < 8; nch++) {
        int col = c * NF + nch * 16 + arow;
        float bb = b2[col];
#pragma unroll
        for (int rg = 0; rg < 4; rg++) {
            int noder = node0 + kgrp * 4 + rg;
            if (noder < NND) phi[(size_t)noder * 384 + col] = acc[nch][rg] + bb;
        }
    }
}

// ---------------- per-node edge reduction via MFMA, slim epilogue ----------------
// t-trick: t = (a<lim) ? cos(pi*a/5) : -1  =>  w = 0.5*(t+1), pads contribute 0.
// Sum(w)     = 0.5*(Sum(t) + 16*ntiles)
// Sum(w*dir) = 0.5*(Sum(t*dir) + Sum_rows(dir))   (identity holds row-wise, pads included)
__global__ __launch_bounds__(256) void reduce3_k(const int* __restrict__ offsets,
                                                 const float4* __restrict__ payload,
                                                 const float* __restrict__ phi,
                                                 const float* __restrict__ v,
                                                 const unsigned short* __restrict__ WrP,
                                                 float* __restrict__ dv,
                                                 float* __restrict__ ds) {
    int lane = threadIdx.x & 63;
    int la = lane & 15, kg = lane >> 4;
    int gw = blockIdx.x * 4 + (threadIdx.x >> 6);
    int nw = gridDim.x * 4;

    bf16x8 wrf[24];
#pragma unroll
    for (int ft = 0; ft < 24; ft++)
        wrf[ft] = *(const bf16x8*)(WrP + (size_t)((ft << 6) + lane) * 8);

    for (int j = gw; j < NND; j += nw) {
        int beg = offsets[j], end = offsets[j + 1];
        int deg = end - beg;
        float a0[8], a1[8], sdx[8], sdy[8], sdz[8];
        float DX = 0.f, DY = 0.f, DZ = 0.f;
#pragma unroll
        for (int i = 0; i < 8; i++) { a0[i] = 0.f; a1[i] = 0.f; sdx[i] = 0.f; sdy[i] = 0.f; sdz[i] = 0.f; }

        for (int base = beg; base < end; base += 16) {
            int cnt = end - base; if (cnt > 16) cnt = 16;
            float4 p = payload[base + (la < cnt ? la : cnt - 1)];
            // --- build A fragment: row = la (edge), k = kg*8 + j2 ---
            float nc = fmaxf(p.w, FEPS);
            float invd = 1.0f / (nc + FEPS);
            union { unsigned short u[8]; bf16x8 v8; } af;
#pragma unroll
            for (int j2 = 0; j2 < 8; j2++) {
                int k = kg * 8 + j2;
                // sin((k+1)*pi/5*nc) = sin(2*pi * (k+1)*0.1 * nc)  [revolutions]
                float sv = __builtin_amdgcn_sinf((float)(k + 1) * 0.1f * nc) * invd;
                sv = fminf(fmaxf(sv, -1.f), 1.f);
                unsigned short b = f2bf(sv);
                af.u[j2] = (k < NRBF) ? b : (unsigned short)((k == NRBF) ? 0x3F80 : 0);
            }
            // --- per-row dir + cutoff limit (pads: lim=-inf -> t=-1 -> w=0) ---
            float dx[4], dy[4], dz[4], lim[4];
#pragma unroll
            for (int rr = 0; rr < 4; rr++) {
                int er = kg * 4 + rr;
                dx[rr] = __shfl(p.x, er);
                dy[rr] = __shfl(p.y, er);
                dz[rr] = __shfl(p.z, er);
                lim[rr] = (er < cnt) ? FCUT : -3.4e38f;
            }
            DX += dx[0] + dx[1] + dx[2] + dx[3];
            DY += dy[0] + dy[1] + dy[2] + dy[3];
            DZ += dz[0] + dz[1] + dz[2] + dz[3];
            // --- 24 feature tiles: D = rbf @ Wr(+br) ---
#pragma unroll
            for (int ft = 0; ft < 24; ft++) {
                f32x4 d = __builtin_amdgcn_mfma_f32_16x16x32_bf16(af.v8, wrf[ft], (f32x4)(0.0f), 0, 0, 0);
#pragma unroll
                for (int rr = 0; rr < 4; rr++) {
                    float a = d[rr];
                    float c = __builtin_amdgcn_cosf(a * 0.1f);  // cos(pi*a/5)
                    float t = (a < lim[rr]) ? c : -1.0f;
                    if (ft < 8)       a0[ft] += t;
                    else if (ft < 16) a1[ft - 8] += t;
                    else {
                        sdx[ft - 16] = fmaf(t, dx[rr], sdx[ft - 16]);
                        sdy[ft - 16] = fmaf(t, dy[rr], sdy[ft - 16]);
                        sdz[ft - 16] = fmaf(t, dz[rr], sdz[ft - 16]);
                    }
                }
            }
        }
        // --- butterfly reduce across the 4 kg groups ---
#pragma unroll
        for (int i = 0; i < 8; i++) {
            a0[i] += __shfl_xor(a0[i], 16);  a0[i] += __shfl_xor(a0[i], 32);
            a1[i] += __shfl_xor(a1[i], 16);  a1[i] += __shfl_xor(a1[i], 32);
            sdx[i] += __shfl_xor(sdx[i], 16); sdx[i] += __shfl_xor(sdx[i], 32);
            sdy[i] += __shfl_xor(sdy[i], 16); sdy[i] += __shfl_xor(sdy[i], 32);
            sdz[i] += __shfl_xor(sdz[i], 16); sdz[i] += __shfl_xor(sdz[i], 32);
        }
        DX += __shfl_xor(DX, 16); DX += __shfl_xor(DX, 32);
        DY += __shfl_xor(DY, 16); DY += __shfl_xor(DY, 32);
        DZ += __shfl_xor(DZ, 16); DZ += __shfl_xor(DZ, 32);
        float R = (float)(((deg + 15) >> 4) << 4);
        // --- epilogue: lane (kg,la) writes features f = ff*16+la, ff in {2kg, 2kg+1} ---
#pragma unroll
        for (int ff = 0; ff < 8; ff++) {
            if ((ff >> 1) == kg) {
                int f = ff * 16 + la;
                float sum1 = 0.5f * (a0[ff] + R);
                float sum2 = 0.5f * (a1[ff] + R);
                float sx = 0.5f * (sdx[ff] + DX);
                float sy = 0.5f * (sdy[ff] + DY);
                float sz = 0.5f * (sdz[ff] + DZ);
                float p1 = phi[(size_t)j * 384 + f];
                float p2 = phi[(size_t)j * 384 + 128 + f];
                float p3 = phi[(size_t)j * 384 + 256 + f];
                ds[(size_t)j * NF + f] = p2 * sum2;
                float c1 = p1 * sum1;
                size_t vb = ((size_t)j * NF + f) * 3;
                dv[vb + 0] = fmaf(v[vb + 0], c1, p3 * sx);
                dv[vb + 1] = fmaf(v[vb + 1], c1, p3 * sy);
                dv[vb + 2] = fmaf(v[vb + 2], c1, p3 * sz);
            }
        }
    }
}

extern "C" void kernel_launch(void* const* d_in, const int* in_sizes, int n_in,
                              void* d_out, int out_size, void* d_ws, size_t ws_size,
                              hipStream_t stream) {
    const float* v  = (const float*)d_in[0];
    const float* s  = (const float*)d_in[1];
    const float* r  = (const float*)d_in[2];
    const float* W1 = (const float*)d_in[3];
    const float* b1 = (const float*)d_in[4];
    const float* W2 = (const float*)d_in[5];
    const float* b2 = (const float*)d_in[6];
    const float* Wr = (const float*)d_in[7];
    const float* br = (const float*)d_in[8];

    float* dv = (float*)d_out;                    // NND*NF*3
    float* ds = dv + (size_t)NND * NF * 3;        // NND*NF

    char* ws = (char*)d_ws;
    int* offsets            = (int*)ws;                         // 80,128 B
    int* cursor             = (int*)(ws + 80128);               // 80,128 B
    float* payload          = (float*)(ws + 160256);            // 5,120,000 B
    unsigned short* hbuf    = (unsigned short*)(ws + 5280256);  // 5,120,000 B
    unsigned short* Wp1     = (unsigned short*)(ws + 10400256); //    32,768 B
    unsigned short* Wp2     = (unsigned short*)(ws + 10433024); //    98,304 B
    unsigned short* WrP     = (unsigned short*)(ws + 10531328); //    24,576 B
    float* phi              = (float*)(ws + 10555904);          // 30,720,000 B

    // 1. CSR build: histogram -> scan -> scatter
    hipMemsetAsync(cursor, 0, NND * sizeof(int), stream);
    hist_k<<<(NE + 255) / 256, 256, 0, stream>>>(r, cursor);
    scan_k<<<1, 1024, 0, stream>>>(cursor, offsets);
    scatter_k<<<(NE + 255) / 256, 256, 0, stream>>>(r, cursor, (float4*)payload);

    // 2. pack all weights into bf16 B-fragments (one launch)
    pack_all_k<<<38, 256, 0, stream>>>(W1, W2, Wr, br, Wp1, Wp2, WrP);

    // 3. node MLP via MFMA
    int nodeBlocks = (NND + 63) / 64;  // 313
    mlp1_k<<<nodeBlocks, 256, 0, stream>>>(s, Wp1, b1, hbuf);
    mlp2_k<<<dim3(nodeBlocks, 3), 256, 0, stream>>>(hbuf, Wp2, b2, phi);

    // 4. per-node edge reduction via MFMA + outputs
    reduce3_k<<<1024, 256, 0, stream>>>(offsets, (const float4*)payload, phi, v, WrP, dv, ds);
}